// Round 1
// 150.605 us; speedup vs baseline: 1.1081x; 1.1081x over previous
//
#include <hip/hip_runtime.h>
#include <hip/hip_bf16.h>

#define N_NODES 50000
#define N_EDGES 800000
#define DIM     128
#define N_STRIPS (N_NODES / 16)               // 3125 exact: 16-row strips
#define N_BKT    196                          // bucket = dst >> 8
#define EDGE_CHUNKS 196                       // chunks of 4096 edges
#define BCAP     8192                         // global bucket region cap (mean 4096, 64 sigma)
#define EBUF_CAP 7168                         // LDS sorted-edge cap (mean 4096, 48 sigma)
#define AGS      68                           // agg LDS row stride (dwords): 16B-aligned frags, conflict-free
#define GEMM_BLOCKS ((N_STRIPS + 3) / 4)      // 782
#define FRONT_BLOCKS (GEMM_BLOCKS + EDGE_CHUNKS) // 978

typedef short short8 __attribute__((ext_vector_type(8)));
typedef float floatx4 __attribute__((ext_vector_type(4)));

// fp32 -> bf16 (RNE) bit pattern
__device__ inline unsigned short f2bf(float f) {
    __hip_bfloat16 h = __float2bfloat16(f);
    return *reinterpret_cast<unsigned short*>(&h);
}

// ---------------------------------------------------------------------------
// Dispatch 1: pack W1 (blocks 0-7) and W2 (blocks 8-15) into MFMA B-fragment
// order; block 16 zeroes the global bucket counters.
// slot s=(ks*8+nt)*64+lane holds 8 bf16: B[ks*32+(lane>>4)*8+j][nt*16+(lane&15)]
// ---------------------------------------------------------------------------
__global__ __launch_bounds__(256) void pre_pack(
    const float* __restrict__ W1, const float* __restrict__ W2,
    uint4* __restrict__ p1, uint4* __restrict__ p2, int* __restrict__ bcnt)
{
    const int blk = blockIdx.x;
    const int t   = threadIdx.x;
    if (blk < 8) {
        const int s    = blk * 256 + t;                  // 0..2047
        const int lane = s & 63;
        const int nt   = (s >> 6) & 7;
        const int ks   = s >> 9;
        const int m    = lane & 15;
        const int q    = lane >> 4;
        unsigned short e[8];
        #pragma unroll
        for (int j = 0; j < 8; ++j)
            e[j] = f2bf(W1[(ks * 32 + q * 8 + j) * DIM + nt * 16 + m]);
        uint4 o;
        o.x = (unsigned)e[0] | ((unsigned)e[1] << 16);
        o.y = (unsigned)e[2] | ((unsigned)e[3] << 16);
        o.z = (unsigned)e[4] | ((unsigned)e[5] << 16);
        o.w = (unsigned)e[6] | ((unsigned)e[7] << 16);
        p1[s] = o;
    } else if (blk < 16) {
        // B[k][n] = W2[n][k]  (x @ W2^T)
        const int s    = (blk - 8) * 256 + t;
        const int lane = s & 63;
        const int nt   = (s >> 6) & 7;
        const int ks   = s >> 9;
        const int m    = lane & 15;
        const int q    = lane >> 4;
        const float4 f0 = *reinterpret_cast<const float4*>(&W2[(nt * 16 + m) * DIM + ks * 32 + q * 8]);
        const float4 f1 = *reinterpret_cast<const float4*>(&W2[(nt * 16 + m) * DIM + ks * 32 + q * 8 + 4]);
        unsigned short e[8];
        e[0] = f2bf(f0.x); e[1] = f2bf(f0.y); e[2] = f2bf(f0.z); e[3] = f2bf(f0.w);
        e[4] = f2bf(f1.x); e[5] = f2bf(f1.y); e[6] = f2bf(f1.z); e[7] = f2bf(f1.w);
        uint4 o;
        o.x = (unsigned)e[0] | ((unsigned)e[1] << 16);
        o.y = (unsigned)e[2] | ((unsigned)e[3] << 16);
        o.z = (unsigned)e[4] | ((unsigned)e[5] << 16);
        o.w = (unsigned)e[6] | ((unsigned)e[7] << 16);
        p2[s] = o;
    } else {
        bcnt[t] = 0;                                     // 256 counters (196 used)
    }
}

// ---------------------------------------------------------------------------
// Dispatch 2: GEMM1 (blocks [0,782)) co-scheduled with bucket scatter
// (blocks [782,978)). Scatter replaces hist->scan->scatter: LDS histogram,
// one global atomicAdd per (chunk,bucket) reserves a range in the bucket's
// fixed-capacity region, LDS cursors order within the chunk.
// ---------------------------------------------------------------------------
__global__ __launch_bounds__(256) void front(
    const float* __restrict__ x, const float* __restrict__ bias,
    const int* __restrict__ src, const int* __restrict__ dst,
    const float* __restrict__ vals, const uint4* __restrict__ p1,
    unsigned short* __restrict__ support, int* __restrict__ bcnt,
    int2* __restrict__ bucketed)
{
    __shared__ int bh[256];
    __shared__ int rcur[256];
    const int t = threadIdx.x;

    if (blockIdx.x < GEMM_BLOCKS) {
        // ---------------- GEMM1: support = bf16(x @ W1 + b) ----------------
        const int wave  = t >> 6;
        const int lane  = t & 63;
        const int strip = blockIdx.x * 4 + wave;
        if (strip >= N_STRIPS) return;
        const int m = lane & 15;
        const int q = lane >> 4;
        const int row = strip * 16 + m;

        short8 a[4];
        const float4* xr = reinterpret_cast<const float4*>(&x[(size_t)row * DIM]);
        #pragma unroll
        for (int ks = 0; ks < 4; ++ks) {
            const float4 f0 = xr[ks * 8 + q * 2];
            const float4 f1 = xr[ks * 8 + q * 2 + 1];
            short8 tt;
            tt[0] = (short)f2bf(f0.x); tt[1] = (short)f2bf(f0.y);
            tt[2] = (short)f2bf(f0.z); tt[3] = (short)f2bf(f0.w);
            tt[4] = (short)f2bf(f1.x); tt[5] = (short)f2bf(f1.y);
            tt[6] = (short)f2bf(f1.z); tt[7] = (short)f2bf(f1.w);
            a[ks] = tt;
        }

        floatx4 acc[8];
        #pragma unroll
        for (int nt = 0; nt < 8; ++nt) { acc[nt][0]=0.f; acc[nt][1]=0.f; acc[nt][2]=0.f; acc[nt][3]=0.f; }

        const short8* Bp = (const short8*)p1;
        #pragma unroll
        for (int ks = 0; ks < 4; ++ks) {
            #pragma unroll
            for (int nt = 0; nt < 8; ++nt) {
                const short8 bf = Bp[(ks * 8 + nt) * 64 + lane];
                acc[nt] = __builtin_amdgcn_mfma_f32_16x16x32_bf16(a[ks], bf, acc[nt], 0, 0, 0);
            }
        }

        #pragma unroll
        for (int nt = 0; nt < 8; ++nt) {
            const float bb = bias[nt * 16 + m];
            #pragma unroll
            for (int i = 0; i < 4; ++i) {
                const int r = strip * 16 + q * 4 + i;
                support[(size_t)r * DIM + nt * 16 + m] = f2bf(acc[nt][i] + bb);
            }
        }
    } else {
        // ---------------- bucket scatter via atomic range reservation -------
        const int chunk = blockIdx.x - GEMM_BLOCKS;
        bh[t] = 0;
        __syncthreads();
        const int base   = chunk * 4096;
        const int navail = min(4096, N_EDGES - base);    // 4096 or 1280; %4==0
        const int4* d4 = reinterpret_cast<const int4*>(dst + base);
        #pragma unroll
        for (int i = 0; i < 4; ++i) {
            const int j = t + i * 256;
            if (j * 4 < navail) {
                const int4 d = d4[j];
                atomicAdd(&bh[d.x >> 8], 1);
                atomicAdd(&bh[d.y >> 8], 1);
                atomicAdd(&bh[d.z >> 8], 1);
                atomicAdd(&bh[d.w >> 8], 1);
            }
        }
        __syncthreads();
        // reserve [r, r+bh[t]) in bucket t's region
        rcur[t] = t * BCAP + atomicAdd(&bcnt[t], bh[t]);
        __syncthreads();
        const int4*   s4 = reinterpret_cast<const int4*>(src + base);
        const float4* v4 = reinterpret_cast<const float4*>(vals + base);
        #pragma unroll
        for (int i = 0; i < 4; ++i) {
            const int j = t + i * 256;
            if (j * 4 < navail) {
                const int4   s = s4[j];
                const int4   d = d4[j];
                const float4 v = v4[j];
                int p;
                p = atomicAdd(&rcur[d.x >> 8], 1);
                bucketed[p] = make_int2((s.x & 0xFFFF) | ((d.x & 0xFF) << 16), __float_as_int(v.x));
                p = atomicAdd(&rcur[d.y >> 8], 1);
                bucketed[p] = make_int2((s.y & 0xFFFF) | ((d.y & 0xFF) << 16), __float_as_int(v.y));
                p = atomicAdd(&rcur[d.z >> 8], 1);
                bucketed[p] = make_int2((s.z & 0xFFFF) | ((d.z & 0xFF) << 16), __float_as_int(v.z));
                p = atomicAdd(&rcur[d.w >> 8], 1);
                bucketed[p] = make_int2((s.w & 0xFFFF) | ((d.w & 0xFF) << 16), __float_as_int(v.w));
            }
        }
    }
}

// ---------------------------------------------------------------------------
// Dispatch 3: one block (1024 thr, 16 waves) per bucket of 256 nodes.
//  A: counting-sort the bucket's edges into LDS (ebuf)            [57 KB]
//  B: per-wave strip gather, register f32 accumulate, relu,
//     bf16 agg rows -> LDS (stride AGS: conflict-free both ways)  [68 KB]
//  C: GEMM2 (MFMA) + bias + row L2-norm straight from LDS agg.
// Total LDS 127 KB -> 1 block/CU. Kills packed+agg global round trips.
// ---------------------------------------------------------------------------
__global__ __launch_bounds__(1024) void agg_gemm2(
    const unsigned int* __restrict__ sup, const int2* __restrict__ bucketed,
    const int* __restrict__ bcnt, const short8* __restrict__ Bp,
    const float* __restrict__ bias, float* __restrict__ out)
{
    __shared__ int2 ebuf[EBUF_CAP];            // 57344 B
    __shared__ unsigned int agg[256 * AGS];    // 69632 B
    __shared__ int cnt[256];
    __shared__ int coff[256];
    __shared__ int cur[256];

    const int b = blockIdx.x;
    const int t = threadIdx.x;
    int nE = bcnt[b];
    if (nE > EBUF_CAP) nE = EBUF_CAP;          // 48-sigma guard, never taken
    const int base = b * BCAP;

    // ---- phase A: counting sort by dst&255 into ebuf ----
    if (t < 256) cnt[t] = 0;
    __syncthreads();
    for (int i = t; i < nE; i += 1024)
        atomicAdd(&cnt[(bucketed[base + i].x >> 16) & 255], 1);
    __syncthreads();
    if (t < 256) coff[t] = cnt[t];
    __syncthreads();
    for (int off = 1; off < 256; off <<= 1) {
        int u = 0;
        if (t < 256 && t >= off) u = coff[t - off];
        __syncthreads();
        if (t < 256 && t >= off) coff[t] += u;
        __syncthreads();
    }
    if (t < 256) cur[t] = coff[t] - cnt[t];    // exclusive prefix
    __syncthreads();
    for (int i = t; i < nE; i += 1024) {
        const int2 e = bucketed[base + i];
        const int  n = (e.x >> 16) & 255;
        const int  p = atomicAdd(&cur[n], 1);
        ebuf[p] = e;
    }
    __syncthreads();

    // ---- phase B: per-wave strip gather (lane owns dims 2*lane, 2*lane+1) ----
    const int w    = t >> 6;
    const int lane = t & 63;
    for (int nl = w * 16; nl < w * 16 + 16; ++nl) {
        const int end = cur[nl];               // = excl + cnt after scatter
        const int beg = end - cnt[nl];
        float ax = 0.f, ay = 0.f;
        int j = beg;
        for (; j + 7 < end; j += 8) {
            int2 e[8];
            unsigned int u[8];
            #pragma unroll
            for (int k = 0; k < 8; ++k) e[k] = ebuf[j + k];
            #pragma unroll
            for (int k = 0; k < 8; ++k) u[k] = sup[(size_t)(e[k].x & 0xFFFF) * 64 + lane];
            #pragma unroll
            for (int k = 0; k < 8; ++k) {
                const float v = __int_as_float(e[k].y);
                ax += __uint_as_float(u[k] << 16) * v;
                ay += __uint_as_float(u[k] & 0xffff0000u) * v;
            }
        }
        for (; j + 3 < end; j += 4) {
            int2 e[4];
            unsigned int u[4];
            #pragma unroll
            for (int k = 0; k < 4; ++k) e[k] = ebuf[j + k];
            #pragma unroll
            for (int k = 0; k < 4; ++k) u[k] = sup[(size_t)(e[k].x & 0xFFFF) * 64 + lane];
            #pragma unroll
            for (int k = 0; k < 4; ++k) {
                const float v = __int_as_float(e[k].y);
                ax += __uint_as_float(u[k] << 16) * v;
                ay += __uint_as_float(u[k] & 0xffff0000u) * v;
            }
        }
        for (; j < end; ++j) {
            const int2 e0 = ebuf[j];
            const unsigned int u0 = sup[(size_t)(e0.x & 0xFFFF) * 64 + lane];
            const float v0 = __int_as_float(e0.y);
            ax += __uint_as_float(u0 << 16) * v0;
            ay += __uint_as_float(u0 & 0xffff0000u) * v0;
        }
        ax = fmaxf(ax, 0.f);
        ay = fmaxf(ay, 0.f);
        agg[nl * AGS + lane] = (unsigned int)f2bf(ax) | ((unsigned int)f2bf(ay) << 16);
    }
    __syncthreads();

    // ---- phase C: out = rownorm(agg @ W2^T + b2), wave w owns strip w ----
    const int row0 = b * 256 + w * 16;
    if (row0 >= N_NODES) return;               // bucket 195 has 5 strips
    const int m = lane & 15;
    const int q = lane >> 4;

    short8 a[4];
    #pragma unroll
    for (int ks = 0; ks < 4; ++ks) {
        const uint4 t4 = *reinterpret_cast<const uint4*>(&agg[(w * 16 + m) * AGS + ks * 16 + q * 4]);
        a[ks] = *reinterpret_cast<const short8*>(&t4);
    }

    floatx4 acc[8];
    #pragma unroll
    for (int nt = 0; nt < 8; ++nt) { acc[nt][0]=0.f; acc[nt][1]=0.f; acc[nt][2]=0.f; acc[nt][3]=0.f; }

    #pragma unroll
    for (int ks = 0; ks < 4; ++ks) {
        #pragma unroll
        for (int nt = 0; nt < 8; ++nt) {
            const short8 bf = Bp[(ks * 8 + nt) * 64 + lane];
            acc[nt] = __builtin_amdgcn_mfma_f32_16x16x32_bf16(a[ks], bf, acc[nt], 0, 0, 0);
        }
    }

    #pragma unroll
    for (int nt = 0; nt < 8; ++nt) {
        const float bb = bias[nt * 16 + m];
        #pragma unroll
        for (int i = 0; i < 4; ++i) acc[nt][i] += bb;
    }

    float sq[4] = {0.f, 0.f, 0.f, 0.f};
    #pragma unroll
    for (int nt = 0; nt < 8; ++nt)
        #pragma unroll
        for (int i = 0; i < 4; ++i) sq[i] += acc[nt][i] * acc[nt][i];
    #pragma unroll
    for (int i = 0; i < 4; ++i) {
        #pragma unroll
        for (int mask = 1; mask < 16; mask <<= 1)
            sq[i] += __shfl_xor(sq[i], mask);
        sq[i] = 1.0f / sqrtf(sq[i]);
    }

    #pragma unroll
    for (int nt = 0; nt < 8; ++nt) {
        #pragma unroll
        for (int i = 0; i < 4; ++i) {
            const int r = row0 + q * 4 + i;
            out[(size_t)r * DIM + nt * 16 + m] = acc[nt][i] * sq[i];
        }
    }
}

// ---------------------------------------------------------------------------
extern "C" void kernel_launch(void* const* d_in, const int* in_sizes, int n_in,
                              void* d_out, int out_size, void* d_ws, size_t ws_size,
                              hipStream_t stream) {
    const float* x    = (const float*)d_in[0];
    const float* vals = (const float*)d_in[1];
    const float* W_gc = (const float*)d_in[2];
    const float* b_gc = (const float*)d_in[3];
    const float* W2   = (const float*)d_in[4];
    const float* b2   = (const float*)d_in[5];
    const int*   src  = (const int*)d_in[6];
    const int*   dst  = (const int*)d_in[7];

    float* out = (float*)d_out;

    // ws layout (16B-aligned). support must be in ws, NOT d_out: dispatch 3
    // reads support (phase B) while other blocks write out (phase C).
    const size_t SUP_B = (size_t)N_NODES * DIM * 2;      // 12,800,000 (bf16)
    const size_t BUK_B = (size_t)N_BKT * BCAP * 8;       // 12,845,056
    char* wsb = (char*)d_ws;
    unsigned short* support = (unsigned short*)wsb;
    int2* bucketed = (int2*)(wsb + SUP_B);
    int*  bcnt     = (int*)(wsb + SUP_B + BUK_B);
    uint4* pw1     = (uint4*)(wsb + SUP_B + BUK_B + 1024);
    uint4* pw2     = (uint4*)(wsb + SUP_B + BUK_B + 1024 + 32768);

    // 1. pack W1/W2 fragments + zero bucket counters
    pre_pack<<<17, 256, 0, stream>>>(W_gc, W2, pw1, pw2, bcnt);

    // 2. GEMM1 || bucket scatter (atomic range reservation)
    front<<<FRONT_BLOCKS, 256, 0, stream>>>(
        x, b_gc, src, dst, vals, pw1, support, bcnt, bucketed);

    // 3. per-bucket: LDS sort -> register gather -> GEMM2 + norm
    agg_gemm2<<<N_BKT, 1024, 0, stream>>>(
        (const unsigned int*)support, bucketed, bcnt, (const short8*)pw2, b2, out);
}

// Round 2
// 148.374 us; speedup vs baseline: 1.1248x; 1.0150x over previous
//
#include <hip/hip_runtime.h>
#include <hip/hip_bf16.h>

#define N_NODES 50000
#define N_EDGES 800000
#define DIM     128
#define N_STRIPS (N_NODES / 16)               // 3125 exact: 16-row strips
#define N_BKT    782                          // bucket = dst >> 6 (64 nodes/bucket)
#define EDGE_CHUNKS 196                       // chunks of 4096 edges
#define BCAP     1536                         // global bucket region cap (mean 1024, 16 sigma)
#define EBUF_CAP 1408                         // LDS sorted-edge cap (mean 1024, 12 sigma)
#define AGS      68                           // agg LDS row stride (dwords): 16B-aligned, 2-way-max banks
#define GEMM_BLOCKS ((N_STRIPS + 3) / 4)      // 782
#define FRONT_BLOCKS (GEMM_BLOCKS + EDGE_CHUNKS) // 978

typedef short short8 __attribute__((ext_vector_type(8)));
typedef float floatx4 __attribute__((ext_vector_type(4)));

// fp32 -> bf16 (RNE) bit pattern
__device__ inline unsigned short f2bf(float f) {
    __hip_bfloat16 h = __float2bfloat16(f);
    return *reinterpret_cast<unsigned short*>(&h);
}

// ---------------------------------------------------------------------------
// Dispatch 1: pack W1 (blocks 0-7) and W2 (blocks 8-15) into MFMA B-fragment
// order; block 16 zeroes the global bucket counters.
// slot s=(ks*8+nt)*64+lane holds 8 bf16: B[ks*32+(lane>>4)*8+j][nt*16+(lane&15)]
// ---------------------------------------------------------------------------
__global__ __launch_bounds__(256) void pre_pack(
    const float* __restrict__ W1, const float* __restrict__ W2,
    uint4* __restrict__ p1, uint4* __restrict__ p2, int* __restrict__ bcnt)
{
    const int blk = blockIdx.x;
    const int t   = threadIdx.x;
    if (blk < 8) {
        const int s    = blk * 256 + t;                  // 0..2047
        const int lane = s & 63;
        const int nt   = (s >> 6) & 7;
        const int ks   = s >> 9;
        const int m    = lane & 15;
        const int q    = lane >> 4;
        unsigned short e[8];
        #pragma unroll
        for (int j = 0; j < 8; ++j)
            e[j] = f2bf(W1[(ks * 32 + q * 8 + j) * DIM + nt * 16 + m]);
        uint4 o;
        o.x = (unsigned)e[0] | ((unsigned)e[1] << 16);
        o.y = (unsigned)e[2] | ((unsigned)e[3] << 16);
        o.z = (unsigned)e[4] | ((unsigned)e[5] << 16);
        o.w = (unsigned)e[6] | ((unsigned)e[7] << 16);
        p1[s] = o;
    } else if (blk < 16) {
        // B[k][n] = W2[n][k]  (x @ W2^T)
        const int s    = (blk - 8) * 256 + t;
        const int lane = s & 63;
        const int nt   = (s >> 6) & 7;
        const int ks   = s >> 9;
        const int m    = lane & 15;
        const int q    = lane >> 4;
        const float4 f0 = *reinterpret_cast<const float4*>(&W2[(nt * 16 + m) * DIM + ks * 32 + q * 8]);
        const float4 f1 = *reinterpret_cast<const float4*>(&W2[(nt * 16 + m) * DIM + ks * 32 + q * 8 + 4]);
        unsigned short e[8];
        e[0] = f2bf(f0.x); e[1] = f2bf(f0.y); e[2] = f2bf(f0.z); e[3] = f2bf(f0.w);
        e[4] = f2bf(f1.x); e[5] = f2bf(f1.y); e[6] = f2bf(f1.z); e[7] = f2bf(f1.w);
        uint4 o;
        o.x = (unsigned)e[0] | ((unsigned)e[1] << 16);
        o.y = (unsigned)e[2] | ((unsigned)e[3] << 16);
        o.z = (unsigned)e[4] | ((unsigned)e[5] << 16);
        o.w = (unsigned)e[6] | ((unsigned)e[7] << 16);
        p2[s] = o;
    } else {
        for (int i = t; i < 800; i += 256) bcnt[i] = 0;  // 782 used
    }
}

// ---------------------------------------------------------------------------
// Dispatch 2: bucket scatter (blocks [0,196)) co-scheduled with GEMM1
// (blocks [196,978)). Scatter first so the latency-heavy phase overlaps the
// MFMA-heavy phase. Per chunk: LDS histogram (782 buckets), one global
// atomicAdd per (chunk,bucket) reserves a range, LDS cursors within chunk.
// ---------------------------------------------------------------------------
__global__ __launch_bounds__(256) void front(
    const float* __restrict__ x, const float* __restrict__ bias,
    const int* __restrict__ src, const int* __restrict__ dst,
    const float* __restrict__ vals, const uint4* __restrict__ p1,
    unsigned short* __restrict__ support, int* __restrict__ bcnt,
    int2* __restrict__ bucketed)
{
    __shared__ int bh[800];
    __shared__ int rcur[800];
    const int t = threadIdx.x;

    if (blockIdx.x < EDGE_CHUNKS) {
        // ---------------- bucket scatter via atomic range reservation -------
        const int chunk = blockIdx.x;
        for (int i = t; i < 800; i += 256) bh[i] = 0;
        __syncthreads();
        const int base   = chunk * 4096;
        const int navail = min(4096, N_EDGES - base);    // 4096 or 1280; %4==0
        const int4* d4 = reinterpret_cast<const int4*>(dst + base);
        #pragma unroll
        for (int i = 0; i < 4; ++i) {
            const int j = t + i * 256;
            if (j * 4 < navail) {
                const int4 d = d4[j];
                atomicAdd(&bh[d.x >> 6], 1);
                atomicAdd(&bh[d.y >> 6], 1);
                atomicAdd(&bh[d.z >> 6], 1);
                atomicAdd(&bh[d.w >> 6], 1);
            }
        }
        __syncthreads();
        // reserve [r, r+bh[b]) in bucket b's region
        for (int b = t; b < N_BKT; b += 256)
            rcur[b] = b * BCAP + atomicAdd(&bcnt[b], bh[b]);
        __syncthreads();
        const int4*   s4 = reinterpret_cast<const int4*>(src + base);
        const float4* v4 = reinterpret_cast<const float4*>(vals + base);
        #pragma unroll
        for (int i = 0; i < 4; ++i) {
            const int j = t + i * 256;
            if (j * 4 < navail) {
                const int4   s = s4[j];
                const int4   d = d4[j];
                const float4 v = v4[j];
                int p;
                p = atomicAdd(&rcur[d.x >> 6], 1);
                bucketed[p] = make_int2((s.x & 0xFFFF) | ((d.x & 63) << 16), __float_as_int(v.x));
                p = atomicAdd(&rcur[d.y >> 6], 1);
                bucketed[p] = make_int2((s.y & 0xFFFF) | ((d.y & 63) << 16), __float_as_int(v.y));
                p = atomicAdd(&rcur[d.z >> 6], 1);
                bucketed[p] = make_int2((s.z & 0xFFFF) | ((d.z & 63) << 16), __float_as_int(v.z));
                p = atomicAdd(&rcur[d.w >> 6], 1);
                bucketed[p] = make_int2((s.w & 0xFFFF) | ((d.w & 63) << 16), __float_as_int(v.w));
            }
        }
    } else {
        // ---------------- GEMM1: support = bf16(x @ W1 + b) ----------------
        const int wave  = t >> 6;
        const int lane  = t & 63;
        const int strip = (blockIdx.x - EDGE_CHUNKS) * 4 + wave;
        if (strip >= N_STRIPS) return;
        const int m = lane & 15;
        const int q = lane >> 4;
        const int row = strip * 16 + m;

        short8 a[4];
        const float4* xr = reinterpret_cast<const float4*>(&x[(size_t)row * DIM]);
        #pragma unroll
        for (int ks = 0; ks < 4; ++ks) {
            const float4 f0 = xr[ks * 8 + q * 2];
            const float4 f1 = xr[ks * 8 + q * 2 + 1];
            short8 tt;
            tt[0] = (short)f2bf(f0.x); tt[1] = (short)f2bf(f0.y);
            tt[2] = (short)f2bf(f0.z); tt[3] = (short)f2bf(f0.w);
            tt[4] = (short)f2bf(f1.x); tt[5] = (short)f2bf(f1.y);
            tt[6] = (short)f2bf(f1.z); tt[7] = (short)f2bf(f1.w);
            a[ks] = tt;
        }

        floatx4 acc[8];
        #pragma unroll
        for (int nt = 0; nt < 8; ++nt) { acc[nt][0]=0.f; acc[nt][1]=0.f; acc[nt][2]=0.f; acc[nt][3]=0.f; }

        const short8* Bp = (const short8*)p1;
        #pragma unroll
        for (int ks = 0; ks < 4; ++ks) {
            #pragma unroll
            for (int nt = 0; nt < 8; ++nt) {
                const short8 bf = Bp[(ks * 8 + nt) * 64 + lane];
                acc[nt] = __builtin_amdgcn_mfma_f32_16x16x32_bf16(a[ks], bf, acc[nt], 0, 0, 0);
            }
        }

        #pragma unroll
        for (int nt = 0; nt < 8; ++nt) {
            const float bb = bias[nt * 16 + m];
            #pragma unroll
            for (int i = 0; i < 4; ++i) {
                const int r = strip * 16 + q * 4 + i;
                support[(size_t)r * DIM + nt * 16 + m] = f2bf(acc[nt][i] + bb);
            }
        }
    }
}

// ---------------------------------------------------------------------------
// Dispatch 3: one block (256 thr, 4 waves) per 64-node bucket.
//  A: counting-sort the bucket's edges into LDS (ebuf)            [11 KB]
//  B: gather, 4 edges per VMEM instruction: lane l loads uint4 (8 dims) of
//     edge (l>>4); node-end shfl-reduce over lane quarters. relu, bf16 ->
//     agg LDS (stride AGS).                                       [17 KB]
//  C: GEMM2 (MFMA) + bias + row L2-norm straight from LDS agg.
// 29.4 KB LDS -> 5 blocks/CU capacity; 782 blocks cover all 256 CUs.
// ---------------------------------------------------------------------------
__global__ __launch_bounds__(256) void agg_gemm2(
    const unsigned int* __restrict__ sup, const int2* __restrict__ bucketed,
    const int* __restrict__ bcnt, const short8* __restrict__ Bp,
    const float* __restrict__ bias, float* __restrict__ out)
{
    __shared__ int2 ebuf[EBUF_CAP];            // 11264 B
    __shared__ unsigned int agg[64 * AGS];     // 17408 B
    __shared__ int cnt[64];
    __shared__ int coff[64];
    __shared__ int cur[64];

    const int b = blockIdx.x;
    const int t = threadIdx.x;
    int nE = bcnt[b];
    if (nE > EBUF_CAP) nE = EBUF_CAP;          // 12-sigma guard, never taken
    const int base = b * BCAP;

    // ---- phase A: counting sort by dst&63 into ebuf ----
    if (t < 64) cnt[t] = 0;
    __syncthreads();
    for (int i = t; i < nE; i += 256)
        atomicAdd(&cnt[(bucketed[base + i].x >> 16) & 63], 1);
    __syncthreads();
    if (t < 64) coff[t] = cnt[t];
    __syncthreads();
    for (int off = 1; off < 64; off <<= 1) {
        int u = 0;
        if (t < 64 && t >= off) u = coff[t - off];
        __syncthreads();
        if (t < 64 && t >= off) coff[t] += u;
        __syncthreads();
    }
    if (t < 64) cur[t] = coff[t] - cnt[t];     // exclusive prefix
    __syncthreads();
    for (int i = t; i < nE; i += 256) {
        const int2 e = bucketed[base + i];
        const int  n = (e.x >> 16) & 63;
        const int  p = atomicAdd(&cur[n], 1);
        ebuf[p] = e;
    }
    __syncthreads();

    // ---- phase B: wave w -> nodes w*16..+16; 4 edges per VMEM inst ----
    const int w    = t >> 6;
    const int lane = t & 63;
    const int g    = lane >> 4;                // edge sub-slot 0..3
    const int dl   = lane & 15;                // dim block: dims 8*dl..+8

    for (int nl = w * 16; nl < w * 16 + 16; ++nl) {
        const int end = cur[nl];               // = excl + cnt after scatter
        const int c   = cnt[nl];
        const int beg = end - c;
        float acc[8];
        #pragma unroll
        for (int k = 0; k < 8; ++k) acc[k] = 0.f;

        const int nI = (c + 3) >> 2;           // instructions (4 edges each)
        auto step = [&](int it) {
            const int  idx = beg + it * 4 + g;
            const bool vld = idx < end;
            const int2 e   = ebuf[vld ? idx : beg];
            const float val = vld ? __int_as_float(e.y) : 0.f;
            const uint4 u = *reinterpret_cast<const uint4*>(
                &sup[(size_t)(e.x & 0xFFFF) * 64 + dl * 4]);
            acc[0] += __uint_as_float(u.x << 16)          * val;
            acc[1] += __uint_as_float(u.x & 0xffff0000u)  * val;
            acc[2] += __uint_as_float(u.y << 16)          * val;
            acc[3] += __uint_as_float(u.y & 0xffff0000u)  * val;
            acc[4] += __uint_as_float(u.z << 16)          * val;
            acc[5] += __uint_as_float(u.z & 0xffff0000u)  * val;
            acc[6] += __uint_as_float(u.w << 16)          * val;
            acc[7] += __uint_as_float(u.w & 0xffff0000u)  * val;
        };
        int it = 0;
        for (; it + 3 < nI; it += 4) { step(it); step(it+1); step(it+2); step(it+3); }
        for (; it < nI; ++it) step(it);

        // combine partial sums across the 4 lane-quarters (g dimension)
        #pragma unroll
        for (int k = 0; k < 8; ++k) {
            acc[k] += __shfl_xor(acc[k], 16);
            acc[k] += __shfl_xor(acc[k], 32);
        }
        if (dl == lane) {                      // lanes 0..15 write the row
            uint4 o;
            o.x = (unsigned)f2bf(fmaxf(acc[0],0.f)) | ((unsigned)f2bf(fmaxf(acc[1],0.f)) << 16);
            o.y = (unsigned)f2bf(fmaxf(acc[2],0.f)) | ((unsigned)f2bf(fmaxf(acc[3],0.f)) << 16);
            o.z = (unsigned)f2bf(fmaxf(acc[4],0.f)) | ((unsigned)f2bf(fmaxf(acc[5],0.f)) << 16);
            o.w = (unsigned)f2bf(fmaxf(acc[6],0.f)) | ((unsigned)f2bf(fmaxf(acc[7],0.f)) << 16);
            *reinterpret_cast<uint4*>(&agg[nl * AGS + dl * 4]) = o;
        }
    }
    __syncthreads();

    // ---- phase C: out = rownorm(agg @ W2^T + b2), wave w owns strip w ----
    const int row0 = b * 64 + w * 16;
    if (row0 >= N_NODES) return;               // bucket 781: waves 1-3 idle
    const int m = lane & 15;
    const int q = lane >> 4;

    short8 a[4];
    #pragma unroll
    for (int ks = 0; ks < 4; ++ks) {
        const uint4 t4 = *reinterpret_cast<const uint4*>(&agg[(w * 16 + m) * AGS + ks * 16 + q * 4]);
        a[ks] = *reinterpret_cast<const short8*>(&t4);
    }

    floatx4 acc[8];
    #pragma unroll
    for (int nt = 0; nt < 8; ++nt) { acc[nt][0]=0.f; acc[nt][1]=0.f; acc[nt][2]=0.f; acc[nt][3]=0.f; }

    #pragma unroll
    for (int ks = 0; ks < 4; ++ks) {
        #pragma unroll
        for (int nt = 0; nt < 8; ++nt) {
            const short8 bf = Bp[(ks * 8 + nt) * 64 + lane];
            acc[nt] = __builtin_amdgcn_mfma_f32_16x16x32_bf16(a[ks], bf, acc[nt], 0, 0, 0);
        }
    }

    #pragma unroll
    for (int nt = 0; nt < 8; ++nt) {
        const float bb = bias[nt * 16 + m];
        #pragma unroll
        for (int i = 0; i < 4; ++i) acc[nt][i] += bb;
    }

    float sq[4] = {0.f, 0.f, 0.f, 0.f};
    #pragma unroll
    for (int nt = 0; nt < 8; ++nt)
        #pragma unroll
        for (int i = 0; i < 4; ++i) sq[i] += acc[nt][i] * acc[nt][i];
    #pragma unroll
    for (int i = 0; i < 4; ++i) {
        #pragma unroll
        for (int mask = 1; mask < 16; mask <<= 1)
            sq[i] += __shfl_xor(sq[i], mask);
        sq[i] = 1.0f / sqrtf(sq[i]);
    }

    #pragma unroll
    for (int nt = 0; nt < 8; ++nt) {
        #pragma unroll
        for (int i = 0; i < 4; ++i) {
            const int r = row0 + q * 4 + i;
            out[(size_t)r * DIM + nt * 16 + m] = acc[nt][i] * sq[i];
        }
    }
}

// ---------------------------------------------------------------------------
extern "C" void kernel_launch(void* const* d_in, const int* in_sizes, int n_in,
                              void* d_out, int out_size, void* d_ws, size_t ws_size,
                              hipStream_t stream) {
    const float* x    = (const float*)d_in[0];
    const float* vals = (const float*)d_in[1];
    const float* W_gc = (const float*)d_in[2];
    const float* b_gc = (const float*)d_in[3];
    const float* W2   = (const float*)d_in[4];
    const float* b2   = (const float*)d_in[5];
    const int*   src  = (const int*)d_in[6];
    const int*   dst  = (const int*)d_in[7];

    float* out = (float*)d_out;

    // ws layout (16B-aligned). support must be in ws, NOT d_out: dispatch 3
    // reads support (phase B) while other blocks write out (phase C).
    const size_t SUP_B = (size_t)N_NODES * DIM * 2;      // 12,800,000 (bf16)
    const size_t BUK_B = (size_t)N_BKT * BCAP * 8;       // 9,609,216
    char* wsb = (char*)d_ws;
    unsigned short* support = (unsigned short*)wsb;
    int2* bucketed = (int2*)(wsb + SUP_B);
    int*  bcnt     = (int*)(wsb + SUP_B + BUK_B);
    uint4* pw1     = (uint4*)(wsb + SUP_B + BUK_B + 4096);
    uint4* pw2     = (uint4*)(wsb + SUP_B + BUK_B + 4096 + 32768);

    // 1. pack W1/W2 fragments + zero bucket counters
    pre_pack<<<17, 256, 0, stream>>>(W_gc, W2, pw1, pw2, bcnt);

    // 2. bucket scatter (first: overlaps MFMA blocks) || GEMM1
    front<<<FRONT_BLOCKS, 256, 0, stream>>>(
        x, b_gc, src, dst, vals, pw1, support, bcnt, bucketed);

    // 3. per-bucket: LDS sort -> 4-edge/inst gather -> GEMM2 + norm
    agg_gemm2<<<N_BKT, 256, 0, stream>>>(
        (const unsigned int*)support, bucketed, bcnt, (const short8*)pw2, b2, out);
}